// Round 6
// baseline (252.164 us; speedup 1.0000x reference)
//
#include <hip/hip_runtime.h>

#define BB 256
#define LL 500
#define EE 300
#define HH 10
#define KK 5
#define NF 50          // K*H output features
#define NWAVE 8

#define BP 328         // Bt row stride (bf16): 320 + 8 pad
#define AP 72          // A LDS row stride (bf16): 64 + 8 pad (144 B, 16B-mult)
#define PW 52          // proj ws row stride (fp32)
#define MPB 512        // padded rows per batch in ws
#define NR4 75         // float4 per review row

// ws layout (bytes)
#define WS_BT_BYTES  (64 * BP * 2)     // 41984
#define WS_PROJ_OFF  65536             // proj f32 [BB][MPB][PW] = 27.3 MB

typedef __attribute__((ext_vector_type(8))) short short8;
typedef __attribute__((ext_vector_type(4))) float f32x4;

__device__ __forceinline__ unsigned int f2bf(float x) {
    unsigned int u = __float_as_uint(x);
    return (u + 0x7FFFu + ((u >> 16) & 1u)) >> 16;   // RNE fp32->bf16
}

// ---- K0: build zero-padded bf16 Bt[64][BP] in ws (gather form, no scatter) ----
__global__ void k0_bt(const float* __restrict__ aspProj, short* __restrict__ btw) {
    int j = blockIdx.x * 512 + threadIdx.x;          // over 64*BP = 20992
    if (j >= 64 * BP) return;
    int n = j / BP, e = j - n * BP;
    float v = 0.f;
    if (n < NF && e < EE) v = aspProj[(n / HH) * (EE * HH) + e * HH + (n - (n / HH) * HH)];
    btw[j] = (short)f2bf(v);
}

// ---- K1: GEMM proj = review * aspProj, 4 blocks per batch (128 rows each) ----
__global__ __launch_bounds__(512, 4) void k1_gemm(
    const float* __restrict__ review,    // (B, L, E)
    const short* __restrict__ btw,       // Bt bf16 [64][BP]
    float* __restrict__ projw)           // [BB][MPB][PW] f32
{
    __shared__ short sB[64 * BP];        // 41984 B
    __shared__ short sA[2][128 * AP];    // 2 * 18432 B  (total LDS ~78.8 KB -> 2 blocks/CU)

    const int tid  = threadIdx.x;
    const int b    = blockIdx.x >> 2;
    const int rq   = blockIdx.x & 3;     // row quarter: rows [rq*128, rq*128+128)
    const int lane = tid & 63;
    const int w    = tid >> 6;           // wave id: rows w*16..w*16+15 (local)
    const int quad = lane >> 4;
    const int m16  = lane & 15;
    const int q    = tid & 15;           // float4 col within 16-wide chunk
    const int r0   = tid >> 4;           // 0..31; rows r0 + 32*i (local)

    // stage Bt: contiguous coalesced copy, 41984 B
    {
        const int4* src = (const int4*)btw;
        int4* dst = (int4*)sB;
        for (int j = tid; j < WS_BT_BYTES / 16; j += 512) dst[j] = src[j];
    }

    // clamped per-thread row pointers (4 rows each)
    const float4* rev4 = (const float4*)review + (size_t)b * LL * NR4;
    const float4* rp[4];
#pragma unroll
    for (int i = 0; i < 4; ++i) {
        int r = rq * 128 + r0 + 32 * i;
        rp[i] = rev4 + (size_t)((r < LL) ? r : (LL - 1)) * NR4;
    }

    // chunk 0 loads (cols 0..15, all < 75)
    float4 ld[4];
#pragma unroll
    for (int i = 0; i < 4; ++i) ld[i] = rp[i][q];

    // store chunk 0 -> buf 0
#pragma unroll
    for (int i = 0; i < 4; ++i) {
        int r = r0 + 32 * i;
        uint2 pk;
        pk.x = f2bf(ld[i].x) | (f2bf(ld[i].y) << 16);
        pk.y = f2bf(ld[i].z) | (f2bf(ld[i].w) << 16);
        *(uint2*)&sA[0][r * AP + q * 4] = pk;
    }
    __syncthreads();

    f32x4 acc[4];
#pragma unroll
    for (int ni = 0; ni < 4; ++ni) acc[ni] = (f32x4){0.f, 0.f, 0.f, 0.f};

#pragma unroll
    for (int c = 0; c < 5; ++c) {
        // prefetch chunk c+1 (unconditional, clamped col)
        if (c + 1 < 5) {
            int fq = (c + 1) * 16 + q;
            if (fq > NR4 - 1) fq = NR4 - 1;           // k>=300 hits Bt zero cols
#pragma unroll
            for (int i = 0; i < 4; ++i) ld[i] = rp[i][fq];
        }
        // mfma on buf[c&1]: 2 k-steps of 32
        const short* Ac = sA[c & 1];
#pragma unroll
        for (int s = 0; s < 2; ++s) {
            short8 af = *(const short8*)&Ac[(w * 16 + m16) * AP + s * 32 + quad * 8];
            short8 bf[4];
#pragma unroll
            for (int ni = 0; ni < 4; ++ni)
                bf[ni] = *(const short8*)&sB[(ni * 16 + m16) * BP + c * 64 + s * 32 + quad * 8];
#pragma unroll
            for (int ni = 0; ni < 4; ++ni)
                acc[ni] = __builtin_amdgcn_mfma_f32_16x16x32_bf16(af, bf[ni], acc[ni], 0, 0, 0);
        }
        // store chunk c+1, single barrier per chunk
        if (c + 1 < 5) {
            short* An = sA[(c + 1) & 1];
#pragma unroll
            for (int i = 0; i < 4; ++i) {
                int r = r0 + 32 * i;
                uint2 pk;
                pk.x = f2bf(ld[i].x) | (f2bf(ld[i].y) << 16);
                pk.y = f2bf(ld[i].z) | (f2bf(ld[i].w) << 16);
                *(uint2*)&An[r * AP + q * 4] = pk;
            }
            __syncthreads();
        }
    }

    // write C (C/D: col = lane&15, row = quad*4 + reg)
    float* pw = projw + (size_t)b * MPB * PW;
    const int rowbase = rq * 128 + w * 16 + quad * 4;
#pragma unroll
    for (int ni = 0; ni < 4; ++ni) {
        int col = ni * 16 + m16;
        if (col < NF) {
#pragma unroll
            for (int r = 0; r < 4; ++r)
                pw[(size_t)(rowbase + r) * PW + col] = acc[ni][r];
        }
    }
}

// ---- K2: window scores + softmax + attn + rep (R3-proven epilogue) ----
__global__ __launch_bounds__(512, 2) void k2_attn(
    const float* __restrict__ projw,     // [BB][MPB][PW]
    const float* __restrict__ aspEmbed,  // (K, 3H)
    float* __restrict__ out)             // [attn (B,K,L)] ++ [rep (B,K,H)]
{
    __shared__ float s_d[3 * KK * MPB];  // 30720 B
    __shared__ float s_red[KK * NWAVE];
    __shared__ float s_rep[NWAVE * NF];
    __shared__ float s_emb[KK * 3 * HH];

    const int tid  = threadIdx.x;
    const int b    = blockIdx.x;
    const int lane = tid & 63;
    const int w    = tid >> 6;
    const int l    = tid;
    const bool vl  = (l < LL);

    if (tid < KK * 3 * HH) s_emb[tid] = aspEmbed[tid];

    // load proj row (13 float4 back-to-back, one wait)
    float4 prv[13];
    const float4* pr4 = (const float4*)(projw + (size_t)b * MPB * PW + (size_t)l * PW);
#pragma unroll
    for (int i = 0; i < 13; ++i) prv[i] = pr4[i];
    float pr[52];
#pragma unroll
    for (int i = 0; i < 13; ++i) {
        pr[4 * i + 0] = prv[i].x; pr[4 * i + 1] = prv[i].y;
        pr[4 * i + 2] = prv[i].z; pr[4 * i + 3] = prv[i].w;
    }
    __syncthreads();                     // s_emb visible

    float d0[KK], d1[KK], d2[KK];
#pragma unroll
    for (int k = 0; k < KK; ++k) {
        float a0 = 0.f, a1 = 0.f, a2 = 0.f;
#pragma unroll
        for (int h = 0; h < HH; ++h) {
            float x = pr[k * HH + h];
            a0 = fmaf(x, s_emb[k * 3 * HH + 3 * h + 0], a0);
            a1 = fmaf(x, s_emb[k * 3 * HH + 3 * h + 1], a1);
            a2 = fmaf(x, s_emb[k * 3 * HH + 3 * h + 2], a2);
        }
        d0[k] = vl ? a0 : 0.f;           // mask garbage pad rows
        d1[k] = vl ? a1 : 0.f;
        d2[k] = vl ? a2 : 0.f;
    }
#pragma unroll
    for (int k = 0; k < KK; ++k) {
        s_d[(0 * KK + k) * MPB + l] = d0[k];
        s_d[(1 * KK + k) * MPB + l] = d1[k];
        s_d[(2 * KK + k) * MPB + l] = d2[k];
    }
    __syncthreads();

    const int lp1 = (l + 1 < MPB) ? l + 1 : MPB - 1;
    float sc[KK];
#pragma unroll
    for (int k = 0; k < KK; ++k) {
        float t0 = (l >= 1) ? s_d[(0 * KK + k) * MPB + l - 1] : 0.f;
        float t1 = s_d[(1 * KK + k) * MPB + l];
        float t2 = s_d[(2 * KK + k) * MPB + lp1];
        sc[k] = vl ? (t0 + t1 + t2) : -1e30f;
    }

    float mx[KK];
#pragma unroll
    for (int k = 0; k < KK; ++k) {
        float m = sc[k];
        for (int s = 32; s > 0; s >>= 1) m = fmaxf(m, __shfl_xor(m, s, 64));
        if (lane == 0) s_red[k * NWAVE + w] = m;
    }
    __syncthreads();
#pragma unroll
    for (int k = 0; k < KK; ++k) {
        float m = s_red[k * NWAVE + 0];
#pragma unroll
        for (int ww = 1; ww < NWAVE; ++ww) m = fmaxf(m, s_red[k * NWAVE + ww]);
        mx[k] = m;
    }
    __syncthreads();
    float ex[KK], sm[KK];
#pragma unroll
    for (int k = 0; k < KK; ++k) {
        ex[k] = __expf(sc[k] - mx[k]);
        float s = ex[k];
        for (int sh = 32; sh > 0; sh >>= 1) s += __shfl_xor(s, sh, 64);
        if (lane == 0) s_red[k * NWAVE + w] = s;
    }
    __syncthreads();
#pragma unroll
    for (int k = 0; k < KK; ++k) {
        float s = 0.f;
#pragma unroll
        for (int ww = 0; ww < NWAVE; ++ww) s += s_red[k * NWAVE + ww];
        sm[k] = s;
    }

#pragma unroll
    for (int k = 0; k < KK; ++k) {
        float wk = ex[k] / sm[k];
        if (vl) out[((size_t)b * KK + k) * LL + l] = wk;
#pragma unroll
        for (int h = 0; h < HH; ++h) {
            float v = pr[k * HH + h] * wk;   // pads: garbage * 0 = 0 (finite)
            for (int sh = 32; sh > 0; sh >>= 1) v += __shfl_xor(v, sh, 64);
            if (lane == 0) s_rep[w * NF + k * HH + h] = v;
        }
    }
    __syncthreads();
    if (tid < NF) {
        float s = 0.f;
#pragma unroll
        for (int ww = 0; ww < NWAVE; ++ww) s += s_rep[ww * NF + tid];
        out[(size_t)BB * KK * LL + (size_t)b * NF + tid] = s;
    }
}

extern "C" void kernel_launch(void* const* d_in, const int* in_sizes, int n_in,
                              void* d_out, int out_size, void* d_ws, size_t ws_size,
                              hipStream_t stream) {
    const float* review   = (const float*)d_in[0];  // (B,L,E)
    const float* aspProj  = (const float*)d_in[1];  // (K,E,H)
    const float* aspEmbed = (const float*)d_in[2];  // (K,3H)
    float* out   = (float*)d_out;
    short* btw   = (short*)d_ws;
    float* projw = (float*)((char*)d_ws + WS_PROJ_OFF);

    k0_bt  <<<dim3((64 * BP + 511) / 512), dim3(512), 0, stream>>>(aspProj, btw);
    k1_gemm<<<dim3(BB * 4), dim3(512), 0, stream>>>(review, btw, projw);
    k2_attn<<<dim3(BB), dim3(512), 0, stream>>>(projw, aspEmbed, out);
}